// Round 3
// baseline (103.187 us; speedup 1.0000x reference)
//
#include <hip/hip_runtime.h>
#include <math.h>

#define POOL 7
#define FH 50
#define FW 50
#define FC 1024
#define FC4 (FC / 4)   // 256 float4 groups per spatial cell

typedef float vf4 __attribute__((ext_vector_type(4)));

static __device__ __forceinline__ vf4 vmax4(vf4 a, vf4 b) {
    vf4 r;
    r.x = fmaxf(a.x, b.x);
    r.y = fmaxf(a.y, b.y);
    r.z = fmaxf(a.z, b.z);
    r.w = fmaxf(a.w, b.w);
    return r;
}

// 256-thread block = 4 waves; each wave handles one (roi, bin_i, bin_j).
// Each thread owns 16 channels (4 x float4): 4 independent loads per cell,
// columns unrolled x2 -> 8 loads in flight before the fmax chain consumes.
// 14700 bins / 4 per block = 3675 blocks; ~8 blocks/CU -> 32 waves/CU.
__global__ __launch_bounds__(256) void roipool_kernel(
    const float* __restrict__ fm,     // [FH, FW, FC]
    const float* __restrict__ rois,   // [N, 4] (y1, x1, y2, x2) normalized
    float* __restrict__ out)          // [N, 7, 7, FC]
{
    const int gid = blockIdx.x * 4 + (threadIdx.x >> 6);  // global bin id
    const int n  = gid / 49;
    const int ij = gid - n * 49;
    const int i  = ij / 7;
    const int j  = ij - i * 7;

    // ROI corners: truncating float->int cast, matching jnp astype(int32)
    const float4 roi = reinterpret_cast<const float4*>(rois)[n];
    const int h0 = (int)((float)FH * roi.x);
    const int w0 = (int)((float)FW * roi.y);
    const int h1 = (int)((float)FH * roi.z);
    const int w1 = (int)((float)FW * roi.w);
    const int rh = h1 - h0;
    const int rw = w1 - w0;
    const int hstep = rh / POOL;
    const int wstep = rw / POOL;

    // bin bounds (region-relative) + empty-bin adjustment
    int sh = i * hstep;
    int eh = (i < POOL - 1) ? (i + 1) * hstep : rh;
    if (sh == eh) { if (eh < rh) eh += 1; else sh -= 1; }
    int sw = j * wstep;
    int ew = (j < POOL - 1) ? (j + 1) * wstep : rw;
    if (sw == ew) { if (ew < rw) ew += 1; else sw -= 1; }

    // global row/col range, clamped to the feature map (mask semantics)
    const int r0 = max(0, h0 + sh);
    const int r1 = min(FH, h0 + eh);
    const int c0 = max(0, w0 + sw);
    const int c1 = min(FW, w0 + ew);

    const int t = threadIdx.x & 63;  // lane within wave

    vf4 acc0 = {-INFINITY, -INFINITY, -INFINITY, -INFINITY};
    vf4 acc1 = acc0, acc2 = acc0, acc3 = acc0;

    const vf4* fm4 = reinterpret_cast<const vf4*>(fm);

    for (int r = r0; r < r1; ++r) {
        const vf4* rowp = fm4 + (size_t)(r * FW) * FC4;
        int c = c0;
        for (; c + 1 < c1; c += 2) {
            const vf4* p0 = rowp + (size_t)c * FC4;
            const vf4* p1 = rowp + (size_t)(c + 1) * FC4;
            vf4 a0 = p0[t];
            vf4 a1 = p0[t + 64];
            vf4 a2 = p0[t + 128];
            vf4 a3 = p0[t + 192];
            vf4 b0 = p1[t];
            vf4 b1 = p1[t + 64];
            vf4 b2 = p1[t + 128];
            vf4 b3 = p1[t + 192];
            acc0 = vmax4(acc0, vmax4(a0, b0));
            acc1 = vmax4(acc1, vmax4(a1, b1));
            acc2 = vmax4(acc2, vmax4(a2, b2));
            acc3 = vmax4(acc3, vmax4(a3, b3));
        }
        if (c < c1) {
            const vf4* p0 = rowp + (size_t)c * FC4;
            vf4 a0 = p0[t];
            vf4 a1 = p0[t + 64];
            vf4 a2 = p0[t + 128];
            vf4 a3 = p0[t + 192];
            acc0 = vmax4(acc0, a0);
            acc1 = vmax4(acc1, a1);
            acc2 = vmax4(acc2, a2);
            acc3 = vmax4(acc3, a3);
        }
    }

    vf4* o = reinterpret_cast<vf4*>(out) + (size_t)gid * FC4;
    __builtin_nontemporal_store(acc0, o + t);
    __builtin_nontemporal_store(acc1, o + t + 64);
    __builtin_nontemporal_store(acc2, o + t + 128);
    __builtin_nontemporal_store(acc3, o + t + 192);
}

extern "C" void kernel_launch(void* const* d_in, const int* in_sizes, int n_in,
                              void* d_out, int out_size, void* d_ws, size_t ws_size,
                              hipStream_t stream) {
    const float* features = (const float*)d_in[0];  // [1,50,50,1024]
    const float* rois     = (const float*)d_in[1];  // [N,4]
    float* out            = (float*)d_out;          // [N,7,7,1024]
    const int N = in_sizes[1] / 4;

    const int nbins = N * POOL * POOL;          // 14700
    dim3 grid((nbins + 3) / 4);                 // 4 bins (waves) per block
    dim3 block(256);
    roipool_kernel<<<grid, block, 0, stream>>>(features, rois, out);
}

// Round 4
// 100.816 us; speedup vs baseline: 1.0235x; 1.0235x over previous
//
#include <hip/hip_runtime.h>
#include <math.h>

#define POOL 7
#define FH 50
#define FW 50
#define FC 1024
#define FC4 (FC / 4)      // 256 float4 groups per spatial cell
#define CHUNKS 4          // channel phases; 64 float4 (256 ch) per phase
#define F4C 64            // float4 per cell per chunk (one wave-wide load)

typedef float vf4 __attribute__((ext_vector_type(4)));

static __device__ __forceinline__ vf4 vmax4(vf4 a, vf4 b) {
    vf4 r;
    r.x = fmaxf(a.x, b.x);
    r.y = fmaxf(a.y, b.y);
    r.z = fmaxf(a.z, b.z);
    r.w = fmaxf(a.w, b.w);
    return r;
}

// Channel-phased RoI max-pool.
// blockIdx.y = channel chunk (dispatched x-fastest => all bins for chunk 0
// run before chunk 1): each phase's fm slice is 50*50*256*4B = 2.56 MB,
// L2-resident per XCD (4 MB). 4 waves per block, one (roi,bin) per wave.
__global__ __launch_bounds__(256) void roipool_kernel(
    const float* __restrict__ fm,     // [FH, FW, FC]
    const float* __restrict__ rois,   // [N, 4] (y1, x1, y2, x2) normalized
    float* __restrict__ out,          // [N, 7, 7, FC]
    int nbins)
{
    const int wave = threadIdx.x >> 6;
    const int lane = threadIdx.x & 63;
    const int gid  = blockIdx.x * 4 + wave;   // bin id: n*49 + i*7 + j
    if (gid >= nbins) return;
    const int chunk = blockIdx.y;

    const int n  = gid / 49;
    const int ij = gid - n * 49;
    const int i  = ij / 7;
    const int j  = ij - i * 7;

    // ROI corners: truncating float->int cast, matching jnp astype(int32)
    const float4 roi = reinterpret_cast<const float4*>(rois)[n];
    const int h0 = (int)((float)FH * roi.x);
    const int w0 = (int)((float)FW * roi.y);
    const int h1 = (int)((float)FH * roi.z);
    const int w1 = (int)((float)FW * roi.w);
    const int rh = h1 - h0;
    const int rw = w1 - w0;
    const int hstep = rh / POOL;
    const int wstep = rw / POOL;

    // bin bounds (region-relative) + empty-bin adjustment
    int sh = i * hstep;
    int eh = (i < POOL - 1) ? (i + 1) * hstep : rh;
    if (sh == eh) { if (eh < rh) eh += 1; else sh -= 1; }
    int sw = j * wstep;
    int ew = (j < POOL - 1) ? (j + 1) * wstep : rw;
    if (sw == ew) { if (ew < rw) ew += 1; else sw -= 1; }

    // global row/col range, clamped to the feature map (mask semantics)
    const int r0 = max(0, h0 + sh);
    const int r1 = min(FH, h0 + eh);
    const int c0 = max(0, w0 + sw);
    const int c1 = min(FW, w0 + ew);

    // this wave's float4 index within a cell for this channel phase
    const int f4 = chunk * F4C + lane;        // [0, 256)

    vf4 acc = {-INFINITY, -INFINITY, -INFINITY, -INFINITY};

    const vf4* fm4 = reinterpret_cast<const vf4*>(fm);

    for (int r = r0; r < r1; ++r) {
        const vf4* rowp = fm4 + (size_t)(r * FW) * FC4 + f4;
        int c = c0;
        for (; c + 1 < c1; c += 2) {
            vf4 a = rowp[(size_t)c * FC4];
            vf4 b = rowp[(size_t)(c + 1) * FC4];
            acc = vmax4(acc, vmax4(a, b));
        }
        if (c < c1) {
            acc = vmax4(acc, rowp[(size_t)c * FC4]);
        }
    }

    vf4* o = reinterpret_cast<vf4*>(out) + (size_t)gid * FC4 + f4;
    __builtin_nontemporal_store(acc, o);
}

extern "C" void kernel_launch(void* const* d_in, const int* in_sizes, int n_in,
                              void* d_out, int out_size, void* d_ws, size_t ws_size,
                              hipStream_t stream) {
    const float* features = (const float*)d_in[0];  // [1,50,50,1024]
    const float* rois     = (const float*)d_in[1];  // [N,4]
    float* out            = (float*)d_out;          // [N,7,7,1024]
    const int N = in_sizes[1] / 4;

    const int nbins = N * POOL * POOL;              // 14700
    dim3 grid((nbins + 3) / 4, CHUNKS);             // x fastest -> chunk phases
    dim3 block(256);
    roipool_kernel<<<grid, block, 0, stream>>>(features, rois, out, nbins);
}

// Round 5
// 96.706 us; speedup vs baseline: 1.0670x; 1.0425x over previous
//
#include <hip/hip_runtime.h>
#include <math.h>

#define POOL 7
#define FH 50
#define FW 50
#define FC 1024
#define FC4 (FC / 4)      // 256 float4 groups per spatial cell
#define CHUNKS 4          // channel chunks; 64 float4 (256 ch) per chunk
#define F4C 64            // float4 per cell per chunk (one wave-wide load)

typedef float vf4 __attribute__((ext_vector_type(4)));

static __device__ __forceinline__ vf4 vmax4(vf4 a, vf4 b) {
    vf4 r;
    r.x = fmaxf(a.x, b.x);
    r.y = fmaxf(a.y, b.y);
    r.z = fmaxf(a.z, b.z);
    r.w = fmaxf(a.w, b.w);
    return r;
}

// XCD-partitioned RoI max-pool.
// Workgroup->XCD is round-robin by linear block id (b % 8), so chunk = b & 3
// pins each XCD to ONE channel chunk for the whole kernel: its 2.56 MB fm
// slice is fetched from HBM once and stays L2-resident (4 MB/XCD), serving
// the ~42x cross-ROI reuse at L2 bandwidth instead of LLC.
// 4 waves per block, one (roi,bin) per wave; bins = (b>>2)*4 + wave.
__global__ __launch_bounds__(256) void roipool_kernel(
    const float* __restrict__ fm,     // [FH, FW, FC]
    const float* __restrict__ rois,   // [N, 4] (y1, x1, y2, x2) normalized
    float* __restrict__ out,          // [N, 7, 7, FC]
    int nbins)
{
    const int b     = blockIdx.x;
    const int chunk = b & (CHUNKS - 1);       // pinned per XCD (b%8 round-robin)
    const int wave  = threadIdx.x >> 6;
    const int lane  = threadIdx.x & 63;
    const int gid   = (b >> 2) * 4 + wave;    // bin id: n*49 + i*7 + j
    if (gid >= nbins) return;

    const int n  = gid / 49;
    const int ij = gid - n * 49;
    const int i  = ij / 7;
    const int j  = ij - i * 7;

    // ROI corners: truncating float->int cast, matching jnp astype(int32)
    const float4 roi = reinterpret_cast<const float4*>(rois)[n];
    const int h0 = (int)((float)FH * roi.x);
    const int w0 = (int)((float)FW * roi.y);
    const int h1 = (int)((float)FH * roi.z);
    const int w1 = (int)((float)FW * roi.w);
    const int rh = h1 - h0;
    const int rw = w1 - w0;
    const int hstep = rh / POOL;
    const int wstep = rw / POOL;

    // bin bounds (region-relative) + empty-bin adjustment
    int sh = i * hstep;
    int eh = (i < POOL - 1) ? (i + 1) * hstep : rh;
    if (sh == eh) { if (eh < rh) eh += 1; else sh -= 1; }
    int sw = j * wstep;
    int ew = (j < POOL - 1) ? (j + 1) * wstep : rw;
    if (sw == ew) { if (ew < rw) ew += 1; else sw -= 1; }

    // global row/col range, clamped to the feature map (mask semantics)
    const int r0 = max(0, h0 + sh);
    const int r1 = min(FH, h0 + eh);
    const int c0 = max(0, w0 + sw);
    const int c1 = min(FW, w0 + ew);

    // this wave's float4 index within a cell for its pinned channel chunk
    const int f4 = chunk * F4C + lane;        // [0, 256)

    vf4 acc = {-INFINITY, -INFINITY, -INFINITY, -INFINITY};

    const vf4* fm4 = reinterpret_cast<const vf4*>(fm);

    for (int r = r0; r < r1; ++r) {
        const vf4* rowp = fm4 + (size_t)(r * FW) * FC4 + f4;
        int c = c0;
        for (; c + 1 < c1; c += 2) {
            vf4 a = rowp[(size_t)c * FC4];
            vf4 b2 = rowp[(size_t)(c + 1) * FC4];
            acc = vmax4(acc, vmax4(a, b2));
        }
        if (c < c1) {
            acc = vmax4(acc, rowp[(size_t)c * FC4]);
        }
    }

    vf4* o = reinterpret_cast<vf4*>(out) + (size_t)gid * FC4 + f4;
    __builtin_nontemporal_store(acc, o);
}

extern "C" void kernel_launch(void* const* d_in, const int* in_sizes, int n_in,
                              void* d_out, int out_size, void* d_ws, size_t ws_size,
                              hipStream_t stream) {
    const float* features = (const float*)d_in[0];  // [1,50,50,1024]
    const float* rois     = (const float*)d_in[1];  // [N,4]
    float* out            = (float*)d_out;          // [N,7,7,1024]
    const int N = in_sizes[1] / 4;

    const int nbins = N * POOL * POOL;              // 14700
    // linear grid: block b -> chunk b&3 (XCD-pinned), bins (b>>2)*4 + wave
    dim3 grid(((nbins + 3) / 4) * CHUNKS);
    dim3 block(256);
    roipool_kernel<<<grid, block, 0, stream>>>(features, rois, out, nbins);
}